// Round 3
// baseline (215.179 us; speedup 1.0000x reference)
//
#include <hip/hip_runtime.h>

// EmbeddingDropout: out[b,s,:] = weight[words[b,s], :] * mask[words[b,s]]
// words: (8,2048) int32; weight: (50257,768) fp32; mask: (50257,1) fp32
// out: (8,2048,768) fp32 = 3,145,728 float4 elements.
//
// R1 lesson: one-block-per-token was latency-bound (3-deep dependent load
// chain, 1 load/thread, ~0.5 TB/s). This version gives each thread 8
// independent element chains (MLP=8), staged so all index loads issue
// before the dependent mask/weight loads.
// R2 lesson: __builtin_nontemporal_store needs a native vector type, not
// HIP_vector_type<float,4>.

#define DIM 768
#define V4_PER_ROW (DIM / 4)   // 192 float4 per row
#define ELEMS 8
#define BLOCK 256

typedef float f4 __attribute__((ext_vector_type(4)));

__global__ __launch_bounds__(BLOCK) void embed_dropout_kernel(
    const int* __restrict__ words,
    const float* __restrict__ weight,
    const float* __restrict__ mask,
    f4* __restrict__ out,
    unsigned int total4) {
    const unsigned int base =
        blockIdx.x * (BLOCK * ELEMS) + threadIdx.x;

    unsigned int ii[ELEMS];
    unsigned int tok[ELEMS];
    unsigned int r[ELEMS];
    int idx[ELEMS];

    // Stage 1: all token-index loads issued back-to-back (independent).
    #pragma unroll
    for (int k = 0; k < ELEMS; ++k) {
        unsigned int i = base + (unsigned int)k * BLOCK;
        if (i >= total4) i = total4 - 1;   // clamp (grid is exact-fit anyway)
        ii[k] = i;
        tok[k] = i / V4_PER_ROW;           // magic-mul, cheap
        r[k] = i - tok[k] * V4_PER_ROW;
        idx[k] = words[tok[k]];
    }

    // Stage 2: all mask + weight loads issued (8 independent chains).
    float scale[ELEMS];
    f4 v[ELEMS];
    #pragma unroll
    for (int k = 0; k < ELEMS; ++k) {
        scale[k] = mask[idx[k]];
        const f4* wrow =
            (const f4*)(weight + (size_t)idx[k] * DIM) + r[k];
        v[k] = *wrow;
    }

    // Stage 3: scale + streaming store (output never re-read by us).
    #pragma unroll
    for (int k = 0; k < ELEMS; ++k) {
        f4 o = v[k] * scale[k];
        __builtin_nontemporal_store(o, &out[ii[k]]);
    }
}

extern "C" void kernel_launch(void* const* d_in, const int* in_sizes, int n_in,
                              void* d_out, int out_size, void* d_ws, size_t ws_size,
                              hipStream_t stream) {
    const int* words = (const int*)d_in[0];       // (8,2048) int32
    const float* weight = (const float*)d_in[1];  // (50257,768) fp32
    const float* mask = (const float*)d_in[2];    // (50257,1) fp32
    f4* out = (f4*)d_out;                         // (8,2048,768) fp32

    const unsigned int total4 = (unsigned int)(out_size / 4);  // 3,145,728
    const unsigned int per_block = BLOCK * ELEMS;              // 2048
    const unsigned int grid = (total4 + per_block - 1) / per_block;  // 1536

    embed_dropout_kernel<<<grid, BLOCK, 0, stream>>>(
        words, weight, mask, out, total4);
}

// Round 4
// 208.016 us; speedup vs baseline: 1.0344x; 1.0344x over previous
//
#include <hip/hip_runtime.h>

// EmbeddingDropout: out[b,s,:] = weight[words[b,s], :] * mask[words[b,s]]
// words: (8,2048) int32; weight: (50257,768) fp32; mask: (50257,1) fp32
// out: (8,2048,768) fp32 = 3,145,728 float4 elements.
//
// R1 lesson: one-block-per-token (MLP=1) == flattened MLP=8 within noise.
// R3 lesson: dur_us is insensitive to kernel structure; rocprof shows our
//   kernel < 92 µs/dispatch while dur_us = 215 -> ~150 µs of the measured
//   time is harness restore/poison traffic (617 MB ws poison = 93 µs,
//   weight restore = 47 µs, out poison = 8 µs).
// This round: exact-fit grid (1024 blocks x 256 thr x 12 f4), no tail
// logic, nontemporal loads (gather reuse distance >> L2/XCD) and stores.

#define DIM 768
#define V4_PER_ROW (DIM / 4)   // 192 float4 per row
#define ELEMS 12
#define BLOCK 256

typedef float f4 __attribute__((ext_vector_type(4)));

__global__ __launch_bounds__(BLOCK) void embed_dropout_kernel(
    const int* __restrict__ words,
    const float* __restrict__ weight,
    const float* __restrict__ mask,
    f4* __restrict__ out) {
    const unsigned int base =
        blockIdx.x * (BLOCK * ELEMS) + threadIdx.x;

    int idx[ELEMS];
    unsigned int r[ELEMS];

    // Stage 1: all token-index loads issued back-to-back (independent).
    #pragma unroll
    for (int k = 0; k < ELEMS; ++k) {
        const unsigned int i = base + (unsigned int)k * BLOCK;
        const unsigned int tok = i / V4_PER_ROW;   // magic-mul
        r[k] = i - tok * V4_PER_ROW;
        idx[k] = words[tok];
    }

    // Stage 2: all mask + weight loads issued (12 independent chains).
    float scale[ELEMS];
    f4 v[ELEMS];
    #pragma unroll
    for (int k = 0; k < ELEMS; ++k) {
        scale[k] = mask[idx[k]];
        const f4* wrow = (const f4*)(weight + (size_t)idx[k] * DIM) + r[k];
        v[k] = __builtin_nontemporal_load(wrow);
    }

    // Stage 3: scale + streaming store (output never re-read by us).
    #pragma unroll
    for (int k = 0; k < ELEMS; ++k) {
        f4 o = v[k] * scale[k];
        __builtin_nontemporal_store(o, &out[base + (unsigned int)k * BLOCK]);
    }
}

extern "C" void kernel_launch(void* const* d_in, const int* in_sizes, int n_in,
                              void* d_out, int out_size, void* d_ws, size_t ws_size,
                              hipStream_t stream) {
    const int* words = (const int*)d_in[0];       // (8,2048) int32
    const float* weight = (const float*)d_in[1];  // (50257,768) fp32
    const float* mask = (const float*)d_in[2];    // (50257,1) fp32
    f4* out = (f4*)d_out;                         // (8,2048,768) fp32

    const unsigned int total4 = (unsigned int)(out_size / 4);        // 3,145,728
    const unsigned int per_block = BLOCK * ELEMS;                    // 3072
    const unsigned int grid = (total4 + per_block - 1) / per_block;  // 1024 exact

    embed_dropout_kernel<<<grid, BLOCK, 0, stream>>>(words, weight, mask, out);
}